// Round 1
// baseline (393.986 us; speedup 1.0000x reference)
//
#include <hip/hip_runtime.h>
#include <hip/hip_bf16.h>

// HardgroupAttention: B=4, H=W=32 (N=1024), C=384, heads=12, hd=32, GP=20.
// Pipeline: qkv GEMM -> group argmax (fp64 acc) -> pass1 (row softmax + mask
// -> column partial sums, deterministic) -> col reduce -> pass2 (recompute,
// apply 1/(colsum+eps), PV) -> proj GEMM.

#define B_    4
#define N_    1024
#define C_    384
#define H3_   1152
#define NH_   12
#define HD_   32
#define GP_   20
#define BH_   48
#define SCALE 0.17677669529663687f

// ---------------- generic NT GEMM: C[M][Nn] = A[M][K] * B[Nn][K]^T ----------
// BM=BN=64, BK=32, 256 threads, 4x4 per thread. M%64==0, Nn%64==0, K%32==0.
__global__ __launch_bounds__(256) void gemm_nt(const float* __restrict__ A,
                                               const float* __restrict__ Bm,
                                               float* __restrict__ Cm,
                                               int M, int Nn, int K) {
  __shared__ float a_s[32][68];
  __shared__ float b_s[32][68];
  int tid = threadIdx.x;
  int tm = tid >> 4, tn = tid & 15;
  int bm = blockIdx.y, bn = blockIdx.x;
  const float* Ab = A + (size_t)bm * 64 * K;
  const float* Bb = Bm + (size_t)bn * 64 * K;
  float acc[4][4] = {};
  for (int kk = 0; kk < K; kk += 32) {
    #pragma unroll
    for (int l = 0; l < 2; ++l) {
      int idx = tid + l * 256;      // 0..511
      int row = idx >> 3;           // 0..63
      int k4  = (idx & 7) * 4;
      float4 av = *(const float4*)(Ab + (size_t)row * K + kk + k4);
      float4 bv = *(const float4*)(Bb + (size_t)row * K + kk + k4);
      a_s[k4 + 0][row] = av.x; a_s[k4 + 1][row] = av.y;
      a_s[k4 + 2][row] = av.z; a_s[k4 + 3][row] = av.w;
      b_s[k4 + 0][row] = bv.x; b_s[k4 + 1][row] = bv.y;
      b_s[k4 + 2][row] = bv.z; b_s[k4 + 3][row] = bv.w;
    }
    __syncthreads();
    #pragma unroll
    for (int k = 0; k < 32; ++k) {
      float4 av = *(const float4*)&a_s[k][tm * 4];
      float4 bv = *(const float4*)&b_s[k][tn * 4];
      float aa[4] = {av.x, av.y, av.z, av.w};
      float bb[4] = {bv.x, bv.y, bv.z, bv.w};
      #pragma unroll
      for (int i = 0; i < 4; ++i)
        #pragma unroll
        for (int j = 0; j < 4; ++j)
          acc[i][j] = fmaf(aa[i], bb[j], acc[i][j]);
    }
    __syncthreads();
  }
  int r0 = bm * 64 + tm * 4, c0 = bn * 64 + tn * 4;
  #pragma unroll
  for (int i = 0; i < 4; ++i) {
    float4 v = {acc[i][0], acc[i][1], acc[i][2], acc[i][3]};
    *(float4*)(Cm + (size_t)(r0 + i) * Nn + c0) = v;
  }
}

// ---------------- group assignment: argmax_g (q_all . W_gp[g]) --------------
// fp64 accumulation so our argmax is the exact-arithmetic one (near-tie safety
// vs the fp32 numpy reference). 320 threads = 16 rows x 20 groups per block.
__global__ __launch_bounds__(320) void group_assign(const float* __restrict__ qkv,
                                                    const float* __restrict__ Wgp,
                                                    int* __restrict__ group) {
  __shared__ double sc[16][GP_];
  int tid = threadIdx.x;
  int r = tid / GP_, g = tid % GP_;
  int n = blockIdx.x * 16 + r;                 // 0..4095 (b*1024+n)
  const float* row = qkv + (size_t)n * H3_;    // q_all = first 384 of qkv row
  const float* w = Wgp + g * C_;
  double acc = 0.0;
  for (int c = 0; c < C_; ++c) acc += (double)row[c] * (double)w[c];
  sc[r][g] = acc;
  __syncthreads();
  if (g == 0) {
    int best = 0; double bv = sc[r][0];
    #pragma unroll
    for (int j = 1; j < GP_; ++j)
      if (sc[r][j] > bv) { bv = sc[r][j]; best = j; }   // strict > == first max
    group[n] = best;
  }
}

// ---------------- pass 1: row softmax + mask -> column partial sums ---------
// grid (64 ntiles, 48 bh); block 256 = 4 waves; wave w owns rows 4w..4w+3;
// lane owns columns lane*4..+3 of each 256-wide m-tile. S[4tiles][4r][4c].
__global__ __launch_bounds__(256) void attn_pass1(const float* __restrict__ qkv,
                                                  const int* __restrict__ group,
                                                  float* __restrict__ colpart) {
  __shared__ float q_s[16][36];
  __shared__ float k_s[256][36];
  __shared__ float cp_s[4][1024];
  __shared__ int   g_s[1024];
  __shared__ int   g_row[16];
  int tid = threadIdx.x;
  int wave = tid >> 6, lane = tid & 63;
  int ntile = blockIdx.x;
  int bh = blockIdx.y;
  int b = bh / NH_, hd = bh % NH_;
  const float* qbase = qkv + (size_t)b * N_ * H3_;
  int n0 = ntile * 16;

  if (tid < 128) {                       // q tile (pre-scaled)
    int r = tid >> 3, d0 = (tid & 7) * 4;
    float4 v = *(const float4*)(qbase + (size_t)(n0 + r) * H3_ + hd * HD_ + d0);
    q_s[r][d0 + 0] = v.x * SCALE; q_s[r][d0 + 1] = v.y * SCALE;
    q_s[r][d0 + 2] = v.z * SCALE; q_s[r][d0 + 3] = v.w * SCALE;
  }
  *(int4*)&g_s[tid * 4] = *(const int4*)(group + b * N_ + tid * 4);
  if (tid < 16) g_row[tid] = group[b * N_ + n0 + tid];

  float S[4][4][4];
  #pragma unroll
  for (int j = 0; j < 4; ++j) {
    __syncthreads();                     // protect k_s (and q_s/g_s on j=0)
    #pragma unroll
    for (int p = 0; p < 8; ++p) {
      int m = p * 32 + (tid >> 3), d0 = (tid & 7) * 4;
      float4 v = *(const float4*)(qbase + (size_t)(j * 256 + m) * H3_ + C_ + hd * HD_ + d0);
      *(float4*)&k_s[m][d0] = v;
    }
    __syncthreads();
    #pragma unroll
    for (int i = 0; i < 4; ++i)
      #pragma unroll
      for (int jj = 0; jj < 4; ++jj) S[j][i][jj] = 0.f;
    #pragma unroll
    for (int d0 = 0; d0 < 32; d0 += 4) {
      float4 qv[4], kv[4];
      #pragma unroll
      for (int i = 0; i < 4; ++i)  qv[i]  = *(const float4*)&q_s[(wave << 2) + i][d0];
      #pragma unroll
      for (int jj = 0; jj < 4; ++jj) kv[jj] = *(const float4*)&k_s[lane * 4 + jj][d0];
      #pragma unroll
      for (int i = 0; i < 4; ++i) {
        #pragma unroll
        for (int jj = 0; jj < 4; ++jj) {
          S[j][i][jj] = fmaf(qv[i].x, kv[jj].x, S[j][i][jj]);
          S[j][i][jj] = fmaf(qv[i].y, kv[jj].y, S[j][i][jj]);
          S[j][i][jj] = fmaf(qv[i].z, kv[jj].z, S[j][i][jj]);
          S[j][i][jj] = fmaf(qv[i].w, kv[jj].w, S[j][i][jj]);
        }
      }
    }
  }

  // row stats (wave-wide: each wave exclusively owns its 4 rows)
  float rinv[4];
  float mx[4];
  #pragma unroll
  for (int i = 0; i < 4; ++i) {
    float m = -1e30f;
    #pragma unroll
    for (int j = 0; j < 4; ++j)
      #pragma unroll
      for (int jj = 0; jj < 4; ++jj) m = fmaxf(m, S[j][i][jj]);
    #pragma unroll
    for (int off = 1; off < 64; off <<= 1) m = fmaxf(m, __shfl_xor(m, off));
    mx[i] = m;
  }
  #pragma unroll
  for (int i = 0; i < 4; ++i) {
    float s = 0.f;
    #pragma unroll
    for (int j = 0; j < 4; ++j)
      #pragma unroll
      for (int jj = 0; jj < 4; ++jj) {
        float e = __expf(S[j][i][jj] - mx[i]);
        S[j][i][jj] = e; s += e;
      }
    #pragma unroll
    for (int off = 1; off < 64; off <<= 1) s += __shfl_xor(s, off);
    rinv[i] = 1.0f / s;
  }

  int gr[4];
  #pragma unroll
  for (int i = 0; i < 4; ++i) gr[i] = g_row[(wave << 2) + i];
  bool samehead = (hd < NH_ / 2);

  #pragma unroll
  for (int j = 0; j < 4; ++j) {
    float cp[4];
    #pragma unroll
    for (int jj = 0; jj < 4; ++jj) {
      int m = j * 256 + lane * 4 + jj;
      int gm = g_s[m];
      float c = 0.f;
      #pragma unroll
      for (int i = 0; i < 4; ++i) {
        bool keep = ((gm == gr[i]) == samehead);
        float pmv = keep ? S[j][i][jj] * rinv[i] : 0.f;
        c += pmv;
      }
      cp[jj] = c;
    }
    float4 v = {cp[0], cp[1], cp[2], cp[3]};
    *(float4*)&cp_s[wave][j * 256 + lane * 4] = v;
  }
  __syncthreads();
  float4 s0 = *(float4*)&cp_s[0][tid * 4];
  float4 s1 = *(float4*)&cp_s[1][tid * 4];
  float4 s2 = *(float4*)&cp_s[2][tid * 4];
  float4 s3 = *(float4*)&cp_s[3][tid * 4];
  float4 r = {s0.x + s1.x + s2.x + s3.x, s0.y + s1.y + s2.y + s3.y,
              s0.z + s1.z + s2.z + s3.z, s0.w + s1.w + s2.w + s3.w};
  *(float4*)(colpart + ((size_t)(bh * 64 + ntile)) * 1024 + tid * 4) = r;
}

// ---------------- colsum = sum over 64 ntile partials -----------------------
__global__ __launch_bounds__(256) void col_reduce(const float* __restrict__ colpart,
                                                  float* __restrict__ colsum) {
  int idx = blockIdx.x * 256 + threadIdx.x;   // 0..49151
  int bh = idx >> 10, m = idx & 1023;
  const float* p = colpart + ((size_t)bh * 64) * 1024 + m;
  float s = 0.f;
  #pragma unroll
  for (int t = 0; t < 64; ++t) s += p[t * 1024];
  colsum[idx] = s;
}

// ---------------- pass 2: recompute probs, renorm by colsum, PV -------------
__global__ __launch_bounds__(256) void attn_pass2(const float* __restrict__ qkv,
                                                  const int* __restrict__ group,
                                                  const float* __restrict__ colsum,
                                                  float* __restrict__ attnout) {
  __shared__ float q_s[16][36];
  __shared__ float smem_kv[256 * 36];   // k_s[m][36] then v_s[d][260] (reuse)
  __shared__ float p_s[16][260];
  __shared__ float inv_s[1024];
  __shared__ int   g_s[1024];
  __shared__ int   g_row[16];
  int tid = threadIdx.x;
  int wave = tid >> 6, lane = tid & 63;
  int ntile = blockIdx.x;
  int bh = blockIdx.y;
  int b = bh / NH_, hd = bh % NH_;
  const float* qbase = qkv + (size_t)b * N_ * H3_;
  int n0 = ntile * 16;

  if (tid < 128) {
    int r = tid >> 3, d0 = (tid & 7) * 4;
    float4 v = *(const float4*)(qbase + (size_t)(n0 + r) * H3_ + hd * HD_ + d0);
    q_s[r][d0 + 0] = v.x * SCALE; q_s[r][d0 + 1] = v.y * SCALE;
    q_s[r][d0 + 2] = v.z * SCALE; q_s[r][d0 + 3] = v.w * SCALE;
  }
  *(int4*)&g_s[tid * 4] = *(const int4*)(group + b * N_ + tid * 4);
  if (tid < 16) g_row[tid] = group[b * N_ + n0 + tid];
  {
    float4 c = *(const float4*)(colsum + (size_t)bh * 1024 + tid * 4);
    inv_s[tid * 4 + 0] = 1.0f / (c.x + 1e-8f);
    inv_s[tid * 4 + 1] = 1.0f / (c.y + 1e-8f);
    inv_s[tid * 4 + 2] = 1.0f / (c.z + 1e-8f);
    inv_s[tid * 4 + 3] = 1.0f / (c.w + 1e-8f);
  }

  float S[4][4][4];
  #pragma unroll
  for (int j = 0; j < 4; ++j) {
    __syncthreads();
    #pragma unroll
    for (int p = 0; p < 8; ++p) {
      int m = p * 32 + (tid >> 3), d0 = (tid & 7) * 4;
      float4 v = *(const float4*)(qbase + (size_t)(j * 256 + m) * H3_ + C_ + hd * HD_ + d0);
      *(float4*)&smem_kv[m * 36 + d0] = v;
    }
    __syncthreads();
    #pragma unroll
    for (int i = 0; i < 4; ++i)
      #pragma unroll
      for (int jj = 0; jj < 4; ++jj) S[j][i][jj] = 0.f;
    #pragma unroll
    for (int d0 = 0; d0 < 32; d0 += 4) {
      float4 qv[4], kv[4];
      #pragma unroll
      for (int i = 0; i < 4; ++i)  qv[i]  = *(const float4*)&q_s[(wave << 2) + i][d0];
      #pragma unroll
      for (int jj = 0; jj < 4; ++jj) kv[jj] = *(const float4*)&smem_kv[(lane * 4 + jj) * 36 + d0];
      #pragma unroll
      for (int i = 0; i < 4; ++i) {
        #pragma unroll
        for (int jj = 0; jj < 4; ++jj) {
          S[j][i][jj] = fmaf(qv[i].x, kv[jj].x, S[j][i][jj]);
          S[j][i][jj] = fmaf(qv[i].y, kv[jj].y, S[j][i][jj]);
          S[j][i][jj] = fmaf(qv[i].z, kv[jj].z, S[j][i][jj]);
          S[j][i][jj] = fmaf(qv[i].w, kv[jj].w, S[j][i][jj]);
        }
      }
    }
  }

  float rinv[4];
  float mx[4];
  #pragma unroll
  for (int i = 0; i < 4; ++i) {
    float m = -1e30f;
    #pragma unroll
    for (int j = 0; j < 4; ++j)
      #pragma unroll
      for (int jj = 0; jj < 4; ++jj) m = fmaxf(m, S[j][i][jj]);
    #pragma unroll
    for (int off = 1; off < 64; off <<= 1) m = fmaxf(m, __shfl_xor(m, off));
    mx[i] = m;
  }
  #pragma unroll
  for (int i = 0; i < 4; ++i) {
    float s = 0.f;
    #pragma unroll
    for (int j = 0; j < 4; ++j)
      #pragma unroll
      for (int jj = 0; jj < 4; ++jj) {
        float e = __expf(S[j][i][jj] - mx[i]);
        S[j][i][jj] = e; s += e;
      }
    #pragma unroll
    for (int off = 1; off < 64; off <<= 1) s += __shfl_xor(s, off);
    rinv[i] = 1.0f / s;
  }

  int gr[4];
  #pragma unroll
  for (int i = 0; i < 4; ++i) gr[i] = g_row[(wave << 2) + i];
  bool samehead = (hd < NH_ / 2);
  #pragma unroll
  for (int j = 0; j < 4; ++j)
    #pragma unroll
    for (int jj = 0; jj < 4; ++jj) {
      int m = j * 256 + lane * 4 + jj;
      int gm = g_s[m];
      float ic = inv_s[m];
      #pragma unroll
      for (int i = 0; i < 4; ++i) {
        bool keep = ((gm == gr[i]) == samehead);
        S[j][i][jj] = keep ? S[j][i][jj] * rinv[i] * ic : 0.f;
      }
    }

  // PV: thread owns rows (nl, nl+1) x col dd; v staged transposed for float4
  float O0 = 0.f, O1 = 0.f;
  int dd = tid & 31, nl = (tid >> 5) * 2;
  #pragma unroll
  for (int j = 0; j < 4; ++j) {
    __syncthreads();                    // previous tile readers done
    #pragma unroll
    for (int i = 0; i < 4; ++i) {
      float4 pv = {S[j][i][0], S[j][i][1], S[j][i][2], S[j][i][3]};
      *(float4*)&p_s[(wave << 2) + i][lane * 4] = pv;
    }
    #pragma unroll
    for (int p = 0; p < 8; ++p) {
      int m = p * 32 + (tid >> 3), d0 = (tid & 7) * 4;
      float4 v = *(const float4*)(qbase + (size_t)(j * 256 + m) * H3_ + 2 * C_ + hd * HD_ + d0);
      smem_kv[(d0 + 0) * 260 + m] = v.x;
      smem_kv[(d0 + 1) * 260 + m] = v.y;
      smem_kv[(d0 + 2) * 260 + m] = v.z;
      smem_kv[(d0 + 3) * 260 + m] = v.w;
    }
    __syncthreads();
    #pragma unroll
    for (int m0 = 0; m0 < 256; m0 += 4) {
      float4 p0 = *(float4*)&p_s[nl][m0];
      float4 p1 = *(float4*)&p_s[nl + 1][m0];
      float4 vv = *(float4*)&smem_kv[dd * 260 + m0];
      O0 = fmaf(p0.x, vv.x, O0); O0 = fmaf(p0.y, vv.y, O0);
      O0 = fmaf(p0.z, vv.z, O0); O0 = fmaf(p0.w, vv.w, O0);
      O1 = fmaf(p1.x, vv.x, O1); O1 = fmaf(p1.y, vv.y, O1);
      O1 = fmaf(p1.z, vv.z, O1); O1 = fmaf(p1.w, vv.w, O1);
    }
  }
  int ng = n0 + nl;
  attnout[((size_t)(b * N_ + ng)) * C_ + hd * HD_ + dd]     = O0;
  attnout[((size_t)(b * N_ + ng + 1)) * C_ + hd * HD_ + dd] = O1;
}

// ---------------- launch ----------------------------------------------------
extern "C" void kernel_launch(void* const* d_in, const int* in_sizes, int n_in,
                              void* d_out, int out_size, void* d_ws, size_t ws_size,
                              hipStream_t stream) {
  const float* x     = (const float*)d_in[0];
  const float* Wqkv  = (const float*)d_in[1];
  const float* Wproj = (const float*)d_in[2];
  const float* Wgp   = (const float*)d_in[3];
  float* out = (float*)d_out;
  float* ws  = (float*)d_ws;

  float* qkv     = ws;                  // 4096*1152          = 4,718,592 f
  float* attnout = ws + 4718592;        // 4096*384           = 1,572,864 f
  float* colpart = ws + 6291456;        // 48*64*1024         = 3,145,728 f
  float* colsum  = ws + 9437184;        // 48*1024            =    49,152 f
  int*   group   = (int*)(ws + 9486336);// 4096 i32           (~38 MB total)

  gemm_nt<<<dim3(18, 64), 256, 0, stream>>>(x, Wqkv, qkv, 4096, H3_, C_);
  group_assign<<<dim3(256), 320, 0, stream>>>(qkv, Wgp, group);
  attn_pass1<<<dim3(64, BH_), 256, 0, stream>>>(qkv, group, colpart);
  col_reduce<<<dim3(192), 256, 0, stream>>>(colpart, colsum);
  attn_pass2<<<dim3(64, BH_), 256, 0, stream>>>(qkv, group, colsum, attnout);
  gemm_nt<<<dim3(6, 64), 256, 0, stream>>>(attnout, Wproj, out, 4096, C_, C_);
}

// Round 2
// 252.000 us; speedup vs baseline: 1.5634x; 1.5634x over previous
//
#include <hip/hip_runtime.h>
#include <hip/hip_bf16.h>

// HardgroupAttention: B=4, N=1024, C=384, heads=12, hd=32, GP=20.
// qkv GEMM -> group argmax (fp64) -> attn_score (QK^T+softmax+mask+rinv ->
// P~ global + col partials) -> col_scale_v (colsum, V' = V/(colsum+eps)) ->
// pv_from_p (out = P~ @ V', streaming GEMM) -> proj GEMM.
// Fallback recompute path retained for small ws_size.

#define B_    4
#define N_    1024
#define C_    384
#define H3_   1152
#define NH_   12
#define HD_   32
#define GP_   20
#define BH_   48
#define SCALE 0.17677669529663687f

// ---------------- generic NT GEMM: C[M][Nn] = A[M][K] * B[Nn][K]^T ----------
__global__ __launch_bounds__(256) void gemm_nt(const float* __restrict__ A,
                                               const float* __restrict__ Bm,
                                               float* __restrict__ Cm,
                                               int M, int Nn, int K) {
  __shared__ float a_s[32][68];
  __shared__ float b_s[32][68];
  int tid = threadIdx.x;
  int tm = tid >> 4, tn = tid & 15;
  int bm = blockIdx.y, bn = blockIdx.x;
  const float* Ab = A + (size_t)bm * 64 * K;
  const float* Bb = Bm + (size_t)bn * 64 * K;
  float acc[4][4] = {};
  for (int kk = 0; kk < K; kk += 32) {
    #pragma unroll
    for (int l = 0; l < 2; ++l) {
      int idx = tid + l * 256;
      int row = idx >> 3;
      int k4  = (idx & 7) * 4;
      float4 av = *(const float4*)(Ab + (size_t)row * K + kk + k4);
      float4 bv = *(const float4*)(Bb + (size_t)row * K + kk + k4);
      a_s[k4 + 0][row] = av.x; a_s[k4 + 1][row] = av.y;
      a_s[k4 + 2][row] = av.z; a_s[k4 + 3][row] = av.w;
      b_s[k4 + 0][row] = bv.x; b_s[k4 + 1][row] = bv.y;
      b_s[k4 + 2][row] = bv.z; b_s[k4 + 3][row] = bv.w;
    }
    __syncthreads();
    #pragma unroll
    for (int k = 0; k < 32; ++k) {
      float4 av = *(const float4*)&a_s[k][tm * 4];
      float4 bv = *(const float4*)&b_s[k][tn * 4];
      float aa[4] = {av.x, av.y, av.z, av.w};
      float bb[4] = {bv.x, bv.y, bv.z, bv.w};
      #pragma unroll
      for (int i = 0; i < 4; ++i)
        #pragma unroll
        for (int j = 0; j < 4; ++j)
          acc[i][j] = fmaf(aa[i], bb[j], acc[i][j]);
    }
    __syncthreads();
  }
  int r0 = bm * 64 + tm * 4, c0 = bn * 64 + tn * 4;
  #pragma unroll
  for (int i = 0; i < 4; ++i) {
    float4 v = {acc[i][0], acc[i][1], acc[i][2], acc[i][3]};
    *(float4*)(Cm + (size_t)(r0 + i) * Nn + c0) = v;
  }
}

// ---------------- group assignment ------------------------------------------
__global__ __launch_bounds__(320) void group_assign(const float* __restrict__ qkv,
                                                    const float* __restrict__ Wgp,
                                                    int* __restrict__ group) {
  __shared__ double sc[16][GP_];
  int tid = threadIdx.x;
  int r = tid / GP_, g = tid % GP_;
  int n = blockIdx.x * 16 + r;
  const float* row = qkv + (size_t)n * H3_;
  const float* w = Wgp + g * C_;
  double acc = 0.0;
  for (int c = 0; c < C_; ++c) acc += (double)row[c] * (double)w[c];
  sc[r][g] = acc;
  __syncthreads();
  if (g == 0) {
    int best = 0; double bv = sc[r][0];
    #pragma unroll
    for (int j = 1; j < GP_; ++j)
      if (sc[r][j] > bv) { bv = sc[r][j]; best = j; }
    group[n] = best;
  }
}

// ---------------- attn_score: softmax+mask+rinv -> P~ + col partials --------
// grid (64 ntiles, nbh); 256 thr = 4 waves; wave owns 4 rows; lane owns
// columns m = j*256 + jj*64 + lane (lane stride 36 fl == 4 mod 32: conflict-free).
template<int WRITE_P>
__global__ __launch_bounds__(256) void attn_score(const float* __restrict__ qkv,
                                                  const int* __restrict__ group,
                                                  float* __restrict__ colpart,
                                                  float* __restrict__ pt,
                                                  int bh0) {
  __shared__ __align__(16) float q_s[16][36];
  __shared__ __align__(16) float k_s[256][36];
  __shared__ int g_s[1024];
  __shared__ int g_row[16];
  int tid = threadIdx.x;
  int wave = tid >> 6, lane = tid & 63;
  int ntile = blockIdx.x;
  int byy = blockIdx.y;
  int bh = bh0 + byy;
  int b = bh / NH_, hd = bh % NH_;
  const float* qbase = qkv + (size_t)b * N_ * H3_;
  int n0 = ntile * 16;

  if (tid < 128) {
    int r = tid >> 3, d0 = (tid & 7) * 4;
    float4 v = *(const float4*)(qbase + (size_t)(n0 + r) * H3_ + hd * HD_ + d0);
    q_s[r][d0 + 0] = v.x * SCALE; q_s[r][d0 + 1] = v.y * SCALE;
    q_s[r][d0 + 2] = v.z * SCALE; q_s[r][d0 + 3] = v.w * SCALE;
  }
  *(int4*)&g_s[tid * 4] = *(const int4*)(group + b * N_ + tid * 4);
  if (tid < 16) g_row[tid] = group[b * N_ + n0 + tid];

  float S[4][4][4];
  #pragma unroll
  for (int j = 0; j < 4; ++j) {
    __syncthreads();
    #pragma unroll
    for (int p = 0; p < 8; ++p) {
      int m = p * 32 + (tid >> 3), d0 = (tid & 7) * 4;
      float4 v = *(const float4*)(qbase + (size_t)(j * 256 + m) * H3_ + C_ + hd * HD_ + d0);
      *(float4*)&k_s[m][d0] = v;
    }
    __syncthreads();
    #pragma unroll
    for (int i = 0; i < 4; ++i)
      #pragma unroll
      for (int jj = 0; jj < 4; ++jj) S[j][i][jj] = 0.f;
    #pragma unroll
    for (int d0 = 0; d0 < 32; d0 += 4) {
      float4 qv[4], kv[4];
      #pragma unroll
      for (int i = 0; i < 4; ++i)   qv[i]  = *(const float4*)&q_s[(wave << 2) + i][d0];
      #pragma unroll
      for (int jj = 0; jj < 4; ++jj) kv[jj] = *(const float4*)&k_s[jj * 64 + lane][d0];
      #pragma unroll
      for (int i = 0; i < 4; ++i) {
        #pragma unroll
        for (int jj = 0; jj < 4; ++jj) {
          S[j][i][jj] = fmaf(qv[i].x, kv[jj].x, S[j][i][jj]);
          S[j][i][jj] = fmaf(qv[i].y, kv[jj].y, S[j][i][jj]);
          S[j][i][jj] = fmaf(qv[i].z, kv[jj].z, S[j][i][jj]);
          S[j][i][jj] = fmaf(qv[i].w, kv[jj].w, S[j][i][jj]);
        }
      }
    }
  }

  float rinv[4], mx[4];
  #pragma unroll
  for (int i = 0; i < 4; ++i) {
    float m = -1e30f;
    #pragma unroll
    for (int j = 0; j < 4; ++j)
      #pragma unroll
      for (int jj = 0; jj < 4; ++jj) m = fmaxf(m, S[j][i][jj]);
    #pragma unroll
    for (int off = 1; off < 64; off <<= 1) m = fmaxf(m, __shfl_xor(m, off));
    mx[i] = m;
  }
  #pragma unroll
  for (int i = 0; i < 4; ++i) {
    float s = 0.f;
    #pragma unroll
    for (int j = 0; j < 4; ++j)
      #pragma unroll
      for (int jj = 0; jj < 4; ++jj) {
        float e = __expf(S[j][i][jj] - mx[i]);
        S[j][i][jj] = e; s += e;
      }
    #pragma unroll
    for (int off = 1; off < 64; off <<= 1) s += __shfl_xor(s, off);
    rinv[i] = 1.0f / s;
  }

  int gr[4];
  #pragma unroll
  for (int i = 0; i < 4; ++i) gr[i] = g_row[(wave << 2) + i];
  bool samehead = (hd < NH_ / 2);

  size_t pbase = ((size_t)byy * N_ + n0 + (wave << 2)) * (size_t)N_;
  float cp[4][4];
  #pragma unroll
  for (int j = 0; j < 4; ++j) {
    #pragma unroll
    for (int jj = 0; jj < 4; ++jj) {
      int m = j * 256 + jj * 64 + lane;
      int gm = g_s[m];
      float c = 0.f;
      #pragma unroll
      for (int i = 0; i < 4; ++i) {
        bool keep = ((gm == gr[i]) == samehead);
        float p = keep ? S[j][i][jj] * rinv[i] : 0.f;
        c += p;
        if (WRITE_P) pt[pbase + (size_t)i * N_ + m] = p;
      }
      cp[j][jj] = c;
    }
  }

  __syncthreads();
  float* cps = &k_s[0][0];          // reuse 9216 floats >= 4096
  #pragma unroll
  for (int j = 0; j < 4; ++j)
    #pragma unroll
    for (int jj = 0; jj < 4; ++jj)
      cps[wave * 1024 + j * 256 + jj * 64 + lane] = cp[j][jj];
  __syncthreads();
  int m4 = tid * 4;
  float4 a0 = *(float4*)&cps[0 * 1024 + m4];
  float4 a1 = *(float4*)&cps[1 * 1024 + m4];
  float4 a2 = *(float4*)&cps[2 * 1024 + m4];
  float4 a3 = *(float4*)&cps[3 * 1024 + m4];
  float4 r = {a0.x + a1.x + a2.x + a3.x, a0.y + a1.y + a2.y + a3.y,
              a0.z + a1.z + a2.z + a3.z, a0.w + a1.w + a2.w + a3.w};
  *(float4*)(colpart + ((size_t)(bh * 64 + ntile)) * 1024 + m4) = r;
}

// ---------------- colsum + V' = V * 1/(colsum+eps) --------------------------
__global__ __launch_bounds__(256) void col_scale_v(const float* __restrict__ colpart,
                                                   const float* __restrict__ qkv,
                                                   float* __restrict__ vprime,
                                                   int bh0) {
  int tid = threadIdx.x;
  int m = blockIdx.x * 256 + tid;
  int bh = bh0 + blockIdx.y;
  int b = bh / NH_, hd = bh % NH_;
  const float* p = colpart + ((size_t)bh * 64) * 1024 + m;
  float s = 0.f;
  #pragma unroll
  for (int t = 0; t < 64; ++t) s += p[t * 1024];
  float inv = 1.0f / (s + 1e-8f);
  const float* vsrc = qkv + ((size_t)b * N_ + m) * H3_ + 2 * C_ + hd * HD_;
  float* vdst = vprime + (size_t)bh * (N_ * HD_) + (size_t)m * HD_;
  #pragma unroll
  for (int d0 = 0; d0 < 32; d0 += 4) {
    float4 v = *(const float4*)(vsrc + d0);
    float4 o = {v.x * inv, v.y * inv, v.z * inv, v.w * inv};
    *(float4*)(vdst + d0) = o;
  }
}

// ---------------- pv_from_p: out = P~ @ V' (streaming) ----------------------
// grid (8 rowtiles, nbh); 256 thr = 4 waves; wave w: m-quarter [w*256,+256)
// for ALL 128 rows. lane: rb=lane>>2 (8 rows rb*8..), db=lane&3 (8 d db*8..).
// Sub-chunk 16 m; Ps XOR-swizzled (phys4 = mo4 ^ (row>>3 & 3)).
__global__ __launch_bounds__(256) void pv_from_p(const float* __restrict__ pt,
                                                 const float* __restrict__ vprime,
                                                 float* __restrict__ attnout,
                                                 int bh0) {
  __shared__ __align__(16) float Ps[4][2048];   // [wave][128 rows x 16 m] 32KB
  __shared__ __align__(16) float Vs[4][512];    // [wave][16 m x 32 d]      8KB
  int tid = threadIdx.x;
  int w = tid >> 6, l = tid & 63;
  int bh = bh0 + blockIdx.y;
  int b = bh / NH_, hd = bh % NH_;
  int r0 = blockIdx.x * 128;
  const float* prow = pt + ((size_t)blockIdx.y * N_ + r0) * (size_t)N_ + w * 256;
  const float* vrow = vprime + (size_t)bh * (N_ * HD_) + (size_t)(w * 256) * HD_;
  int rb = l >> 2, db = l & 3;

  float acc[8][8] = {};
  for (int s = 0; s < 16; ++s) {      // 16 sub-chunks of 16 m
    // stage P~ [128 rows][16 m] (swizzled), 8 float4 per lane
    #pragma unroll
    for (int k = 0; k < 8; ++k) {
      int f = k * 256 + l * 4;
      int row = f >> 4, mo = f & 15;
      float4 v = *(const float4*)(prow + (size_t)row * N_ + s * 16 + mo);
      int phys = ((mo >> 2) ^ ((row >> 3) & 3)) << 2;
      *(float4*)&Ps[w][row * 16 + phys] = v;
    }
    // stage V' [16 m][32 d], 2 float4 per lane
    #pragma unroll
    for (int k = 0; k < 2; ++k) {
      int f = k * 256 + l * 4;
      float4 v = *(const float4*)(vrow + s * 512 + f);
      *(float4*)&Vs[w][f] = v;
    }
    // compute (wave-private buffers: no __syncthreads needed)
    #pragma unroll
    for (int mi4 = 0; mi4 < 4; ++mi4) {
      float4 vv[4][2];
      #pragma unroll
      for (int i = 0; i < 4; ++i) {
        vv[i][0] = *(float4*)&Vs[w][(mi4 * 4 + i) * 32 + db * 8];
        vv[i][1] = *(float4*)&Vs[w][(mi4 * 4 + i) * 32 + db * 8 + 4];
      }
      #pragma unroll
      for (int rr = 0; rr < 8; ++rr) {
        int row = rb * 8 + rr;
        float4 pp = *(float4*)&Ps[w][row * 16 + ((mi4 ^ (rb & 3)) << 2)];
        float pa[4] = {pp.x, pp.y, pp.z, pp.w};
        #pragma unroll
        for (int i = 0; i < 4; ++i) {
          acc[rr][0] = fmaf(pa[i], vv[i][0].x, acc[rr][0]);
          acc[rr][1] = fmaf(pa[i], vv[i][0].y, acc[rr][1]);
          acc[rr][2] = fmaf(pa[i], vv[i][0].z, acc[rr][2]);
          acc[rr][3] = fmaf(pa[i], vv[i][0].w, acc[rr][3]);
          acc[rr][4] = fmaf(pa[i], vv[i][1].x, acc[rr][4]);
          acc[rr][5] = fmaf(pa[i], vv[i][1].y, acc[rr][5]);
          acc[rr][6] = fmaf(pa[i], vv[i][1].z, acc[rr][6]);
          acc[rr][7] = fmaf(pa[i], vv[i][1].w, acc[rr][7]);
        }
      }
    }
  }

  // cross-wave reduce in 2 halves of 64 rows, reusing Ps[w] (2048 = 64x32)
  #pragma unroll
  for (int half = 0; half < 2; ++half) {
    __syncthreads();                  // previous readers done
    if ((rb >> 3) == half) {
      #pragma unroll
      for (int rr = 0; rr < 8; ++rr) {
        int row = rb * 8 + rr;
        int rowl = row - half * 64;
        int sw = (row >> 3) & 3;
        int p0 = ((db * 2) ^ sw) << 2;
        int p1 = ((db * 2 + 1) ^ sw) << 2;
        float4 v0 = {acc[rr][0], acc[rr][1], acc[rr][2], acc[rr][3]};
        float4 v1 = {acc[rr][4], acc[rr][5], acc[rr][6], acc[rr][7]};
        *(float4*)&Ps[w][rowl * 32 + p0] = v0;
        *(float4*)&Ps[w][rowl * 32 + p1] = v1;
      }
    }
    __syncthreads();
    int rowl = tid >> 2, dq = tid & 3;       // 64 rows x 4 d-quarters(8 d)
    int row = half * 64 + rowl;
    int sw = (row >> 3) & 3;
    int q0 = ((dq * 2) ^ sw) << 2;
    int q1 = ((dq * 2 + 1) ^ sw) << 2;
    float4 o0 = {0, 0, 0, 0}, o1 = {0, 0, 0, 0};
    #pragma unroll
    for (int ww = 0; ww < 4; ++ww) {
      float4 t0 = *(float4*)&Ps[ww][rowl * 32 + q0];
      float4 t1 = *(float4*)&Ps[ww][rowl * 32 + q1];
      o0.x += t0.x; o0.y += t0.y; o0.z += t0.z; o0.w += t0.w;
      o1.x += t1.x; o1.y += t1.y; o1.z += t1.z; o1.w += t1.w;
    }
    float* dst = attnout + ((size_t)(b * N_ + r0 + row)) * C_ + hd * HD_ + dq * 8;
    *(float4*)(dst)     = o0;
    *(float4*)(dst + 4) = o1;
  }
}

// ---------------- fallback path (recompute), kept from prior round ----------
__global__ __launch_bounds__(256) void col_reduce(const float* __restrict__ colpart,
                                                  float* __restrict__ colsum) {
  int idx = blockIdx.x * 256 + threadIdx.x;
  int bh = idx >> 10, m = idx & 1023;
  const float* p = colpart + ((size_t)bh * 64) * 1024 + m;
  float s = 0.f;
  #pragma unroll
  for (int t = 0; t < 64; ++t) s += p[t * 1024];
  colsum[idx] = s;
}

__global__ __launch_bounds__(256) void attn_pass2(const float* __restrict__ qkv,
                                                  const int* __restrict__ group,
                                                  const float* __restrict__ colsum,
                                                  float* __restrict__ attnout) {
  __shared__ float q_s[16][36];
  __shared__ float smem_kv[256 * 36];
  __shared__ float p_s[16][260];
  __shared__ float inv_s[1024];
  __shared__ int   g_s[1024];
  __shared__ int   g_row[16];
  int tid = threadIdx.x;
  int wave = tid >> 6, lane = tid & 63;
  int ntile = blockIdx.x;
  int bh = blockIdx.y;
  int b = bh / NH_, hd = bh % NH_;
  const float* qbase = qkv + (size_t)b * N_ * H3_;
  int n0 = ntile * 16;

  if (tid < 128) {
    int r = tid >> 3, d0 = (tid & 7) * 4;
    float4 v = *(const float4*)(qbase + (size_t)(n0 + r) * H3_ + hd * HD_ + d0);
    q_s[r][d0 + 0] = v.x * SCALE; q_s[r][d0 + 1] = v.y * SCALE;
    q_s[r][d0 + 2] = v.z * SCALE; q_s[r][d0 + 3] = v.w * SCALE;
  }
  *(int4*)&g_s[tid * 4] = *(const int4*)(group + b * N_ + tid * 4);
  if (tid < 16) g_row[tid] = group[b * N_ + n0 + tid];
  {
    float4 c = *(const float4*)(colsum + (size_t)bh * 1024 + tid * 4);
    inv_s[tid * 4 + 0] = 1.0f / (c.x + 1e-8f);
    inv_s[tid * 4 + 1] = 1.0f / (c.y + 1e-8f);
    inv_s[tid * 4 + 2] = 1.0f / (c.z + 1e-8f);
    inv_s[tid * 4 + 3] = 1.0f / (c.w + 1e-8f);
  }

  float S[4][4][4];
  #pragma unroll
  for (int j = 0; j < 4; ++j) {
    __syncthreads();
    #pragma unroll
    for (int p = 0; p < 8; ++p) {
      int m = p * 32 + (tid >> 3), d0 = (tid & 7) * 4;
      float4 v = *(const float4*)(qbase + (size_t)(j * 256 + m) * H3_ + C_ + hd * HD_ + d0);
      *(float4*)&smem_kv[m * 36 + d0] = v;
    }
    __syncthreads();
    #pragma unroll
    for (int i = 0; i < 4; ++i)
      #pragma unroll
      for (int jj = 0; jj < 4; ++jj) S[j][i][jj] = 0.f;
    #pragma unroll
    for (int d0 = 0; d0 < 32; d0 += 4) {
      float4 qv[4], kv[4];
      #pragma unroll
      for (int i = 0; i < 4; ++i)  qv[i]  = *(const float4*)&q_s[(wave << 2) + i][d0];
      #pragma unroll
      for (int jj = 0; jj < 4; ++jj) kv[jj] = *(const float4*)&smem_kv[(lane * 4 + jj) * 36 + d0];
      #pragma unroll
      for (int i = 0; i < 4; ++i) {
        #pragma unroll
        for (int jj = 0; jj < 4; ++jj) {
          S[j][i][jj] = fmaf(qv[i].x, kv[jj].x, S[j][i][jj]);
          S[j][i][jj] = fmaf(qv[i].y, kv[jj].y, S[j][i][jj]);
          S[j][i][jj] = fmaf(qv[i].z, kv[jj].z, S[j][i][jj]);
          S[j][i][jj] = fmaf(qv[i].w, kv[jj].w, S[j][i][jj]);
        }
      }
    }
  }

  float rinv[4], mx[4];
  #pragma unroll
  for (int i = 0; i < 4; ++i) {
    float m = -1e30f;
    #pragma unroll
    for (int j = 0; j < 4; ++j)
      #pragma unroll
      for (int jj = 0; jj < 4; ++jj) m = fmaxf(m, S[j][i][jj]);
    #pragma unroll
    for (int off = 1; off < 64; off <<= 1) m = fmaxf(m, __shfl_xor(m, off));
    mx[i] = m;
  }
  #pragma unroll
  for (int i = 0; i < 4; ++i) {
    float s = 0.f;
    #pragma unroll
    for (int j = 0; j < 4; ++j)
      #pragma unroll
      for (int jj = 0; jj < 4; ++jj) {
        float e = __expf(S[j][i][jj] - mx[i]);
        S[j][i][jj] = e; s += e;
      }
    #pragma unroll
    for (int off = 1; off < 64; off <<= 1) s += __shfl_xor(s, off);
    rinv[i] = 1.0f / s;
  }

  int gr[4];
  #pragma unroll
  for (int i = 0; i < 4; ++i) gr[i] = g_row[(wave << 2) + i];
  bool samehead = (hd < NH_ / 2);
  #pragma unroll
  for (int j = 0; j < 4; ++j)
    #pragma unroll
    for (int jj = 0; jj < 4; ++jj) {
      int m = j * 256 + lane * 4 + jj;
      int gm = g_s[m];
      float ic = inv_s[m];
      #pragma unroll
      for (int i = 0; i < 4; ++i) {
        bool keep = ((gm == gr[i]) == samehead);
        S[j][i][jj] = keep ? S[j][i][jj] * rinv[i] * ic : 0.f;
      }
    }

  float O0 = 0.f, O1 = 0.f;
  int dd = tid & 31, nl = (tid >> 5) * 2;
  #pragma unroll
  for (int j = 0; j < 4; ++j) {
    __syncthreads();
    #pragma unroll
    for (int i = 0; i < 4; ++i) {
      float4 pv = {S[j][i][0], S[j][i][1], S[j][i][2], S[j][i][3]};
      *(float4*)&p_s[(wave << 2) + i][lane * 4] = pv;
    }
    #pragma unroll
    for (int p = 0; p < 8; ++p) {
      int m = p * 32 + (tid >> 3), d0 = (tid & 7) * 4;
      float4 v = *(const float4*)(qbase + (size_t)(j * 256 + m) * H3_ + 2 * C_ + hd * HD_ + d0);
      smem_kv[(d0 + 0) * 260 + m] = v.x;
      smem_kv[(d0 + 1) * 260 + m] = v.y;
      smem_kv[(d0 + 2) * 260 + m] = v.z;
      smem_kv[(d0 + 3) * 260 + m] = v.w;
    }
    __syncthreads();
    #pragma unroll
    for (int m0 = 0; m0 < 256; m0 += 4) {
      float4 p0 = *(float4*)&p_s[nl][m0];
      float4 p1 = *(float4*)&p_s[nl + 1][m0];
      float4 vv = *(float4*)&smem_kv[dd * 260 + m0];
      O0 = fmaf(p0.x, vv.x, O0); O0 = fmaf(p0.y, vv.y, O0);
      O0 = fmaf(p0.z, vv.z, O0); O0 = fmaf(p0.w, vv.w, O0);
      O1 = fmaf(p1.x, vv.x, O1); O1 = fmaf(p1.y, vv.y, O1);
      O1 = fmaf(p1.z, vv.z, O1); O1 = fmaf(p1.w, vv.w, O1);
    }
  }
  int ng = n0 + nl;
  attnout[((size_t)(b * N_ + ng)) * C_ + hd * HD_ + dd]     = O0;
  attnout[((size_t)(b * N_ + ng + 1)) * C_ + hd * HD_ + dd] = O1;
}

// ---------------- launch ----------------------------------------------------
extern "C" void kernel_launch(void* const* d_in, const int* in_sizes, int n_in,
                              void* d_out, int out_size, void* d_ws, size_t ws_size,
                              hipStream_t stream) {
  const float* x     = (const float*)d_in[0];
  const float* Wqkv  = (const float*)d_in[1];
  const float* Wproj = (const float*)d_in[2];
  const float* Wgp   = (const float*)d_in[3];
  float* out = (float*)d_out;
  float* ws  = (float*)d_ws;

  float* qkv     = ws;                    // 4,718,592 f
  float* attnout = ws + 4718592;          // 1,572,864 f
  float* colpart = ws + 6291456;          // 3,145,728 f
  float* colsum  = ws + 9437184;          //    49,152 f
  float* vprime  = ws + 9486336;          // 1,572,864 f
  int*   group   = (int*)(ws + 11059200); //     4,096 i
  float* ptilde  = ws + 11063296;         // up to 50,331,648 f

  const size_t baseF = 11063296ull;
  int nchunks = 0, nbh = 0;
  if (ws_size >= (baseF + 48ull * 1024 * 1024) * 4) { nchunks = 1; nbh = 48; }
  else if (ws_size >= (baseF + 24ull * 1024 * 1024) * 4) { nchunks = 2; nbh = 24; }
  else if (ws_size >= (baseF + 12ull * 1024 * 1024) * 4) { nchunks = 4; nbh = 12; }

  gemm_nt<<<dim3(18, 64), 256, 0, stream>>>(x, Wqkv, qkv, 4096, H3_, C_);
  group_assign<<<dim3(256), 320, 0, stream>>>(qkv, Wgp, group);

  if (nchunks > 0) {
    for (int c = 0; c < nchunks; ++c) {
      int bh0 = c * nbh;
      attn_score<1><<<dim3(64, nbh), 256, 0, stream>>>(qkv, group, colpart, ptilde, bh0);
      col_scale_v<<<dim3(4, nbh), 256, 0, stream>>>(colpart, qkv, vprime, bh0);
      pv_from_p<<<dim3(8, nbh), 256, 0, stream>>>(ptilde, vprime, attnout, bh0);
    }
  } else {
    attn_score<0><<<dim3(64, BH_), 256, 0, stream>>>(qkv, group, colpart, nullptr, 0);
    col_reduce<<<dim3(192), 256, 0, stream>>>(colpart, colsum);
    attn_pass2<<<dim3(64, BH_), 256, 0, stream>>>(qkv, group, colsum, attnout);
  }

  gemm_nt<<<dim3(6, 64), 256, 0, stream>>>(attnout, Wproj, out, 4096, C_, C_);
}